// Round 2
// baseline (2633.063 us; speedup 1.0000x reference)
//
#include <hip/hip_runtime.h>
#include <hip/hip_bf16.h>
#include <math.h>

#define B_ 4
#define L_ 1024
#define N_ 4096
#define D_ 1024
#define H_ 16
#define FF_ 2752
#define NL_ 2
#define HD_ 64
#define M_ (B_*N_)   // 16384

typedef short bf16x8 __attribute__((ext_vector_type(8)));
typedef float f32x4 __attribute__((ext_vector_type(4)));

__device__ __forceinline__ float bf2f(short s){
  unsigned int u = ((unsigned int)(unsigned short)s) << 16;
  union { unsigned int u; float f; } c; c.u = u; return c.f;
}
__device__ __forceinline__ short f2bf(float f){
  union { float f; unsigned int u; } c; c.f = f;
  unsigned int u = c.u;
  unsigned int r = (u + 0x7fffu + ((u >> 16) & 1u)) >> 16;
  return (short)r;
}

#define GPTR(p) ((const __attribute__((address_space(1))) void*)(p))
#define LPTR(p) ((__attribute__((address_space(3))) void*)(p))

// ---------------- gather: z[b,n,:] = source[b,n>>2,n] * z_hat[b,n>>2,:] ----------------
__global__ __launch_bounds__(256) void gather_kernel(const float* __restrict__ zh,
                                                     const float* __restrict__ src,
                                                     float* __restrict__ z){
  int idx = blockIdx.x*256 + threadIdx.x;      // M_*D_/4 = 4194304
  int d4 = idx & (D_/4 - 1);
  int n  = (idx >> 8) & (N_-1);
  int b  = idx >> 20;
  int l  = n >> 2;
  float s = src[((size_t)b*L_ + l)*N_ + n];
  float4 zv = *(const float4*)(zh + ((size_t)b*L_ + l)*D_ + d4*4);
  float4 o; o.x=zv.x*s; o.y=zv.y*s; o.z=zv.z*s; o.w=zv.w*s;
  *(float4*)(z + ((size_t)b*N_ + n)*D_ + d4*4) = o;
}

// -------- transpose + fp32->bf16: out[ ((r/bs)*gs + go + r%bs) * ldo + k ] = in[k*Nc + r] -----
__global__ void tconv_kernel(const float* __restrict__ in, short* __restrict__ out,
                             int K, int Nc, int ldo, int bs, int gs, int go){
  __shared__ float tile[32][33];
  int k0 = blockIdx.x*32, r0 = blockIdx.y*32;
  int tx = threadIdx.x, ty = threadIdx.y;
  for (int i = ty; i < 32; i += 8)
    tile[i][tx] = in[(size_t)(k0+i)*Nc + r0 + tx];
  __syncthreads();
  for (int i = ty; i < 32; i += 8){
    int rr = r0 + i;
    int orow = (rr/bs)*gs + go + (rr % bs);
    out[(size_t)orow*ldo + k0 + tx] = f2bf(tile[tx][i]);
  }
}

// ---------------- rope cos/sin table: [N_][32] ----------------
__global__ __launch_bounds__(256) void rope_table_kernel(float* __restrict__ cost, float* __restrict__ sint){
  int idx = blockIdx.x*256 + threadIdx.x;   // N_*32
  int n = idx >> 5, j = idx & 31;
  float inv = __expf(-(float)j * (9.210340371976184f/32.0f)); // 10000^(-j/32)
  float ang = (float)n * inv;
  cost[idx] = cosf(ang);
  sint[idx] = sinf(ang);
}

// ---------------- rmsnorm (fp32 in -> bf16 out), one block per row ----------------
__global__ __launch_bounds__(256) void rmsnorm_kernel(const float* __restrict__ z,
                                                      const float* __restrict__ w,
                                                      short* __restrict__ out){
  int row = blockIdx.x, tid = threadIdx.x;
  const float* x = z + (size_t)row*D_;
  float4 v = *(const float4*)(x + tid*4);
  float ss = v.x*v.x + v.y*v.y + v.z*v.z + v.w*v.w;
  #pragma unroll
  for (int off=32; off>0; off>>=1) ss += __shfl_down(ss, off, 64);
  __shared__ float red[4];
  if ((tid & 63) == 0) red[tid>>6] = ss;
  __syncthreads();
  float ms = (red[0]+red[1]+red[2]+red[3]) * (1.0f/D_);
  float rs = rsqrtf(ms + 1e-6f);
  float4 wv = *(const float4*)(w + tid*4);
  short4 o;
  o.x = f2bf(v.x*rs*wv.x); o.y = f2bf(v.y*rs*wv.y);
  o.z = f2bf(v.z*rs*wv.z); o.w = f2bf(v.w*rs*wv.w);
  *(short4*)(out + (size_t)row*D_ + tid*4) = o;
}

// ---------------- GEMM: C[M][N] = A[M][K-ish](bf16, ld=lda) * Bt[N rows][ld=ldb](bf16) -------
// EPI 0: store bf16 (ld=ldc)
// EPI 1: fp32 += into C (ld=ldc)
// EPI 2: swiglu; Bt rows are (f/16)*32 + sel*16 + f%16 blocks; store silu(g)*u bf16 at feature col
template<int EPI>
__global__ __launch_bounds__(256, 2) void gemm_bt_kernel(
    const short* __restrict__ A, int lda,
    const short* __restrict__ Bt, int ldb,
    void* __restrict__ Cout, int ldc, int K)
{
  __shared__ short Al[128*64];
  __shared__ short Bl[128*64];
  const int tid = threadIdx.x;
  const int wid = tid >> 6;
  const int lane = tid & 63;
  const int wr = wid >> 1, wc = wid & 1;
  const int lrow = lane & 15;
  const int lk   = (lane >> 4) << 3;

  f32x4 acc[4][4];
  #pragma unroll
  for (int i=0;i<4;i++)
    #pragma unroll
    for (int j=0;j<4;j++) acc[i][j] = (f32x4){0.f,0.f,0.f,0.f};

  const size_t abase = (size_t)blockIdx.y * 128 * lda;
  const size_t bbase = (size_t)blockIdx.x * 128 * ldb;

  for (int kt = 0; kt < K; kt += 64) {
    __syncthreads();
    #pragma unroll
    for (int r = 0; r < 4; ++r) {
      int l2 = (r<<8) + tid;              // 0..1023
      int row = l2 >> 3, seg = l2 & 7;
      const short* ga = A  + abase + (size_t)row*lda + kt + (seg<<3);
      const short* gb = Bt + bbase + (size_t)row*ldb + kt + (seg<<3);
      int lbase = (r<<11) + (wid<<9);     // wave-uniform element offset
      __builtin_amdgcn_global_load_lds(GPTR(ga), LPTR(Al + lbase), 16, 0, 0);
      __builtin_amdgcn_global_load_lds(GPTR(gb), LPTR(Bl + lbase), 16, 0, 0);
    }
    __syncthreads();

    #pragma unroll
    for (int kk = 0; kk < 64; kk += 32) {
      bf16x8 af[4], bfr[4];
      #pragma unroll
      for (int mi=0;mi<4;mi++){
        int row = (wr<<6) + (mi<<4) + lrow;
        af[mi] = *(const bf16x8*)(Al + row*64 + kk + lk);
      }
      #pragma unroll
      for (int ni=0;ni<4;ni++){
        int row = (wc<<6) + (ni<<4) + lrow;
        bfr[ni] = *(const bf16x8*)(Bl + row*64 + kk + lk);
      }
      #pragma unroll
      for (int mi=0;mi<4;mi++)
        #pragma unroll
        for (int ni=0;ni<4;ni++)
          acc[mi][ni] = __builtin_amdgcn_mfma_f32_16x16x32_bf16(af[mi], bfr[ni], acc[mi][ni], 0, 0, 0);
    }
  }

  const int crow0 = blockIdx.y*128 + (wr<<6);
  const int ccol0 = blockIdx.x*128 + (wc<<6);

  if (EPI == 2) {
    #pragma unroll
    for (int mi=0;mi<4;mi++){
      #pragma unroll
      for (int p=0;p<2;p++){
        int fcol = (ccol0>>1) + (p<<4) + lrow;
        int rowb = crow0 + (mi<<4) + ((lane>>4)<<2);
        #pragma unroll
        for (int v=0;v<4;v++){
          float g = acc[mi][2*p][v], u = acc[mi][2*p+1][v];
          float a = g * u / (1.0f + __expf(-g));
          ((short*)Cout)[(size_t)(rowb+v)*ldc + fcol] = f2bf(a);
        }
      }
    }
  } else {
    #pragma unroll
    for (int mi=0;mi<4;mi++){
      #pragma unroll
      for (int ni=0;ni<4;ni++){
        int col  = ccol0 + (ni<<4) + lrow;
        int rowb = crow0 + (mi<<4) + ((lane>>4)<<2);
        #pragma unroll
        for (int v=0;v<4;v++){
          float val = acc[mi][ni][v];
          int row = rowb + v;
          if (EPI == 0) ((short*)Cout)[(size_t)row*ldc + col] = f2bf(val);
          else          ((float*)Cout)[(size_t)row*ldc + col] += val;
        }
      }
    }
  }
}

// ---------------- in-place rope on qkv block [4096][3072] (q,k cols only) ----------------
__global__ __launch_bounds__(256) void rope_blk_kernel(short* __restrict__ qkv,
                                                       const float* __restrict__ cosT,
                                                       const float* __restrict__ sinT){
  int idx = blockIdx.x*256 + threadIdx.x;   // 4096*16*2*4 = 524288
  int jg  = idx & 3;
  int sel = (idx>>2) & 1;
  int h   = (idx>>3) & 15;
  int row = idx >> 7;                        // 0..4095 (n within batch)
  size_t base = (size_t)row*3072 + sel*1024 + h*64 + jg*16;
  bf16x8 a = *(bf16x8*)(qkv+base);
  bf16x8 b = *(bf16x8*)(qkv+base+8);
  const float* cp = cosT + (row<<5) + (jg<<3);
  const float* sp = sinT + (row<<5) + (jg<<3);
  float4 c0 = *(const float4*)cp, c1 = *(const float4*)(cp+4);
  float4 s0 = *(const float4*)sp, s1 = *(const float4*)(sp+4);
  float cc[8] = {c0.x,c0.y,c0.z,c0.w,c1.x,c1.y,c1.z,c1.w};
  float ss[8] = {s0.x,s0.y,s0.z,s0.w,s1.x,s1.y,s1.z,s1.w};
  bf16x8 oa, ob;
  #pragma unroll
  for (int t=0;t<4;t++){
    float x1 = bf2f(a[2*t]), x2 = bf2f(a[2*t+1]);
    oa[2*t]   = f2bf(x1*cc[t] - x2*ss[t]);
    oa[2*t+1] = f2bf(x1*ss[t] + x2*cc[t]);
    float y1 = bf2f(b[2*t]), y2 = bf2f(b[2*t+1]);
    ob[2*t]   = f2bf(y1*cc[t+4] - y2*ss[t+4]);
    ob[2*t+1] = f2bf(y1*ss[t+4] + y2*cc[t+4]);
  }
  *(bf16x8*)(qkv+base)   = oa;
  *(bf16x8*)(qkv+base+8) = ob;
}

// ---------------- sliding-window attention on one batch block [4096][3072] ----------------
__global__ __launch_bounds__(256) void attn_kernel(const short* __restrict__ qkv,
                                                   short* __restrict__ o){
  int gid = blockIdx.x*256 + threadIdx.x;   // 4096*16 = 65536
  int h  = gid & 15;
  int nc = gid >> 4;                         // n within batch, 0..4095
  const short* q = qkv + (size_t)nc*3072 + h*64;
  float qr[64];
  #pragma unroll
  for (int i=0;i<8;i++){
    bf16x8 qv = *(const bf16x8*)(q + i*8);
    #pragma unroll
    for (int t=0;t<8;t++) qr[i*8+t] = bf2f(qv[t]) * 0.125f;
  }
  float sc[31];
  float mx = -1e30f;
  #pragma unroll
  for (int t=0;t<31;t++){
    int m = nc - 15 + t;
    int mc = m < 0 ? 0 : (m > N_-1 ? N_-1 : m);
    const short* kp = qkv + (size_t)mc*3072 + 1024 + h*64;
    float dot = 0.f;
    #pragma unroll
    for (int i=0;i<8;i++){
      bf16x8 kv = *(const bf16x8*)(kp + i*8);
      #pragma unroll
      for (int u=0;u<8;u++) dot += qr[i*8+u] * bf2f(kv[u]);
    }
    bool valid = (m>=0) && (m<N_);
    sc[t] = valid ? dot : -1e30f;
    mx = fmaxf(mx, sc[t]);
  }
  float sum = 0.f;
  #pragma unroll
  for (int t=0;t<31;t++){ sc[t] = __expf(sc[t]-mx); sum += sc[t]; }
  float inv = 1.0f/sum;
  float ov[64];
  #pragma unroll
  for (int i=0;i<64;i++) ov[i]=0.f;
  #pragma unroll
  for (int t=0;t<31;t++){
    int m = nc - 15 + t;
    int mc = m < 0 ? 0 : (m > N_-1 ? N_-1 : m);
    const short* vp = qkv + (size_t)mc*3072 + 2048 + h*64;
    float p = sc[t]*inv;
    #pragma unroll
    for (int i=0;i<8;i++){
      bf16x8 vv = *(const bf16x8*)(vp + i*8);
      #pragma unroll
      for (int u=0;u<8;u++) ov[i*8+u] += p * bf2f(vv[u]);
    }
  }
  short* op = o + (size_t)nc*1024 + h*64;
  #pragma unroll
  for (int i=0;i<8;i++){
    bf16x8 wv;
    #pragma unroll
    for (int u=0;u<8;u++) wv[u] = f2bf(ov[i*8+u]);
    *(bf16x8*)(op + i*8) = wv;
  }
}

// ---------------- final rmsnorm + head matmul (V=6), fp32 ----------------
__global__ __launch_bounds__(256) void head_kernel(const float* __restrict__ z,
                                                   const float* __restrict__ fw,
                                                   const float* __restrict__ hw,
                                                   float* __restrict__ out){
  int row = blockIdx.x, tid = threadIdx.x;
  const float* x = z + (size_t)row*D_;
  float4 v = *(const float4*)(x + tid*4);
  float ss = v.x*v.x + v.y*v.y + v.z*v.z + v.w*v.w;
  #pragma unroll
  for (int off=32; off>0; off>>=1) ss += __shfl_down(ss, off, 64);
  __shared__ float red[4];
  if ((tid & 63) == 0) red[tid>>6] = ss;
  __syncthreads();
  float ms = (red[0]+red[1]+red[2]+red[3]) * (1.0f/D_);
  float rs = rsqrtf(ms + 1e-6f);
  float4 wv = *(const float4*)(fw + tid*4);
  float h0 = v.x*rs*wv.x, h1 = v.y*rs*wv.y, h2 = v.z*rs*wv.z, h3 = v.w*rs*wv.w;
  float p[6];
  #pragma unroll
  for (int t=0;t<6;t++){
    const float* hp = hw + (size_t)(tid*4)*6 + t;
    p[t] = h0*hp[0] + h1*hp[6] + h2*hp[12] + h3*hp[18];
  }
  #pragma unroll
  for (int t=0;t<6;t++)
    #pragma unroll
    for (int off=32; off>0; off>>=1) p[t] += __shfl_down(p[t], off, 64);
  __shared__ float wred[4][6];
  if ((tid & 63) == 0)
    #pragma unroll
    for (int t=0;t<6;t++) wred[tid>>6][t] = p[t];
  __syncthreads();
  if (tid < 6)
    out[(size_t)row*6 + tid] = wred[0][tid]+wred[1][tid]+wred[2][tid]+wred[3][tid];
}

extern "C" void kernel_launch(void* const* d_in, const int* in_sizes, int n_in,
                              void* d_out, int out_size, void* d_ws, size_t ws_size,
                              hipStream_t stream)
{
  (void)in_sizes; (void)n_in; (void)out_size; (void)ws_size;
  const float* z_hat  = (const float*)d_in[0];
  const float* source = (const float*)d_in[1];
  const float* wq  = (const float*)d_in[2];
  const float* wk  = (const float*)d_in[3];
  const float* wvp = (const float*)d_in[4];
  const float* wo  = (const float*)d_in[5];
  const float* n1w = (const float*)d_in[6];
  const float* n2w = (const float*)d_in[7];
  const float* w1  = (const float*)d_in[8];
  const float* w3  = (const float*)d_in[9];
  const float* w2  = (const float*)d_in[10];
  const float* fnw = (const float*)d_in[11];
  const float* hw  = (const float*)d_in[12];
  float* out = (float*)d_out;

  // ---- workspace layout (total 127,008,768 B ≈ 121 MiB) ----
  char* ws = (char*)d_ws;
  float* z     = (float*)(ws);                      // 67,108,864
  short* h_b   = (short*)(ws + 67108864);           //  8,388,608  [4096][1024] bf16
  short* qkv_b = (short*)(ws + 75497472);           // 25,165,824  [4096][3072] bf16 (shared with act)
  short* act_b = qkv_b;                             //             [4096][2752] bf16
  short* o_b   = (short*)(ws + 100663296);          //  8,388,608  [4096][1024] bf16
  short* qkvW  = (short*)(ws + 109051904);          //  6,291,456  [3072][1024] (stage A)
  short* woW   = (short*)(ws + 115343360);          //  2,097,152  [1024][1024] (stage A)
  short* w13W  = (short*)(ws + 109051904);          // 11,272,192  [5504][1024] (stage B, reuse)
  short* w2W   = (short*)(ws + 120324096);          //  5,636,096  [1024][2752] (stage B)
  float* cosT  = (float*)(ws + 125960192);          //    524,288
  float* sinT  = (float*)(ws + 126484480);          //    524,288

  dim3 tb(32,8);
  rope_table_kernel<<<512,256,0,stream>>>(cosT, sinT);
  gather_kernel<<<16384,256,0,stream>>>(z_hat, source, z);

  for (int l=0; l<NL_; l++){
    size_t wofs = (size_t)l*D_*D_;
    // ---- stage A weights: qkv (plain rows q|k|v) + wo ----
    tconv_kernel<<<dim3(32,32),tb,0,stream>>>(wq  + wofs, qkvW,               1024,1024,1024, 64,64,0);
    tconv_kernel<<<dim3(32,32),tb,0,stream>>>(wk  + wofs, qkvW + 1024*1024,   1024,1024,1024, 64,64,0);
    tconv_kernel<<<dim3(32,32),tb,0,stream>>>(wvp + wofs, qkvW + 2048*1024,   1024,1024,1024, 64,64,0);
    tconv_kernel<<<dim3(32,32),tb,0,stream>>>(wo  + wofs, woW,                1024,1024,1024, 64,64,0);
    // ---- stage A: per-batch attention path ----
    for (int b=0; b<B_; b++){
      float* zb = z + (size_t)b*N_*D_;
      rmsnorm_kernel<<<N_,256,0,stream>>>(zb, n1w + l*D_, h_b);
      gemm_bt_kernel<0><<<dim3(24,32),256,0,stream>>>(h_b,1024, qkvW,1024, qkv_b,3072, 1024);
      rope_blk_kernel<<<2048,256,0,stream>>>(qkv_b, cosT, sinT);
      attn_kernel<<<256,256,0,stream>>>(qkv_b, o_b);
      gemm_bt_kernel<1><<<dim3(8,32),256,0,stream>>>(o_b,1024, woW,1024, zb,1024, 1024);
    }
    // ---- stage B weights: w13 (16-block interleave) + w2 ----
    tconv_kernel<<<dim3(32,86),tb,0,stream>>>(w1 + (size_t)l*D_*FF_, w13W, 1024,2752,1024, 16,32,0);
    tconv_kernel<<<dim3(32,86),tb,0,stream>>>(w3 + (size_t)l*D_*FF_, w13W, 1024,2752,1024, 16,32,16);
    tconv_kernel<<<dim3(86,32),tb,0,stream>>>(w2 + (size_t)l*FF_*D_, w2W,  2752,1024,2752, 64,64,0);
    // ---- stage B: per-batch FFN ----
    for (int b=0; b<B_; b++){
      float* zb = z + (size_t)b*N_*D_;
      rmsnorm_kernel<<<N_,256,0,stream>>>(zb, n2w + l*D_, h_b);
      gemm_bt_kernel<2><<<dim3(43,32),256,0,stream>>>(h_b,1024, w13W,1024, act_b,2752, 1024);
      gemm_bt_kernel<1><<<dim3(8,32),256,0,stream>>>(act_b,2752, w2W,2752, zb,1024, 2752);
    }
  }
  head_kernel<<<M_,256,0,stream>>>(z, fnw, hw, out);
}

// Round 3
// 1998.850 us; speedup vs baseline: 1.3173x; 1.3173x over previous
//
#include <hip/hip_runtime.h>
#include <hip/hip_bf16.h>
#include <math.h>

#define B_ 4
#define L_ 1024
#define N_ 4096
#define D_ 1024
#define H_ 16
#define FF_ 2752
#define NL_ 2
#define HD_ 64
#define M_ (B_*N_)   // 16384

typedef short bf16x8 __attribute__((ext_vector_type(8)));
typedef float f32x4 __attribute__((ext_vector_type(4)));

__device__ __forceinline__ float bf2f(short s){
  unsigned int u = ((unsigned int)(unsigned short)s) << 16;
  union { unsigned int u; float f; } c; c.u = u; return c.f;
}
__device__ __forceinline__ short f2bf(float f){
  union { float f; unsigned int u; } c; c.f = f;
  unsigned int u = c.u;
  unsigned int r = (u + 0x7fffu + ((u >> 16) & 1u)) >> 16;
  return (short)r;
}

#define GPTR(p) ((const __attribute__((address_space(1))) void*)(p))
#define LPTR(p) ((__attribute__((address_space(3))) void*)(p))

// ---------------- gather: z[b,n,:] = source[b,n>>2,n] * z_hat[b,n>>2,:] ----------------
__global__ __launch_bounds__(256) void gather_kernel(const float* __restrict__ zh,
                                                     const float* __restrict__ src,
                                                     float* __restrict__ z){
  int idx = blockIdx.x*256 + threadIdx.x;      // M_*D_/4 = 4194304
  int d4 = idx & (D_/4 - 1);
  int n  = (idx >> 8) & (N_-1);
  int b  = idx >> 20;
  int l  = n >> 2;
  float s = src[((size_t)b*L_ + l)*N_ + n];
  float4 zv = *(const float4*)(zh + ((size_t)b*L_ + l)*D_ + d4*4);
  float4 o; o.x=zv.x*s; o.y=zv.y*s; o.z=zv.z*s; o.w=zv.w*s;
  *(float4*)(z + ((size_t)b*N_ + n)*D_ + d4*4) = o;
}

// -------- transpose + fp32->bf16: out[ ((r/bs)*gs + go + r%bs) * ldo + k ] = in[k*Nc + r] -----
__global__ void tconv_kernel(const float* __restrict__ in, short* __restrict__ out,
                             int K, int Nc, int ldo, int bs, int gs, int go){
  __shared__ float tile[32][33];
  int k0 = blockIdx.x*32, r0 = blockIdx.y*32;
  int tx = threadIdx.x, ty = threadIdx.y;
  for (int i = ty; i < 32; i += 8)
    tile[i][tx] = in[(size_t)(k0+i)*Nc + r0 + tx];
  __syncthreads();
  for (int i = ty; i < 32; i += 8){
    int rr = r0 + i;
    int orow = (rr/bs)*gs + go + (rr % bs);
    out[(size_t)orow*ldo + k0 + tx] = f2bf(tile[tx][i]);
  }
}

// ---------------- rope cos/sin table: [N_][32] ----------------
__global__ __launch_bounds__(256) void rope_table_kernel(float* __restrict__ cost, float* __restrict__ sint){
  int idx = blockIdx.x*256 + threadIdx.x;   // N_*32
  int n = idx >> 5, j = idx & 31;
  float inv = __expf(-(float)j * (9.210340371976184f/32.0f)); // 10000^(-j/32)
  float ang = (float)n * inv;
  cost[idx] = cosf(ang);
  sint[idx] = sinf(ang);
}

// ---------------- rmsnorm (fp32 in -> bf16 out), one block per row ----------------
__global__ __launch_bounds__(256) void rmsnorm_kernel(const float* __restrict__ z,
                                                      const float* __restrict__ w,
                                                      short* __restrict__ out){
  int row = blockIdx.x, tid = threadIdx.x;
  const float* x = z + (size_t)row*D_;
  float4 v = *(const float4*)(x + tid*4);
  float ss = v.x*v.x + v.y*v.y + v.z*v.z + v.w*v.w;
  #pragma unroll
  for (int off=32; off>0; off>>=1) ss += __shfl_down(ss, off, 64);
  __shared__ float red[4];
  if ((tid & 63) == 0) red[tid>>6] = ss;
  __syncthreads();
  float ms = (red[0]+red[1]+red[2]+red[3]) * (1.0f/D_);
  float rs = rsqrtf(ms + 1e-6f);
  float4 wv = *(const float4*)(w + tid*4);
  short4 o;
  o.x = f2bf(v.x*rs*wv.x); o.y = f2bf(v.y*rs*wv.y);
  o.z = f2bf(v.z*rs*wv.z); o.w = f2bf(v.w*rs*wv.w);
  *(short4*)(out + (size_t)row*D_ + tid*4) = o;
}

// ---------------- GEMM: C[M][N] = A[M][.](bf16, ld=lda) * Bt[N rows][ld=ldb](bf16) -------
// BM=128 fixed; BN template (128 or 64).
// EPI 0: store bf16 (ld=ldc) | EPI 1: fp32 += (ld=ldc) | EPI 2: swiglu (BN=128 only)
template<int EPI, int BN>
__global__ __launch_bounds__(256, 2) void gemm_bt_kernel(
    const short* __restrict__ A, int lda,
    const short* __restrict__ Bt, int ldb,
    void* __restrict__ Cout, int ldc, int K)
{
  constexpr int WC = (BN == 128) ? 2 : 1;   // waves along N
  constexpr int WR = 4 / WC;                // waves along M
  constexpr int MI = (BN == 128) ? 4 : 2;   // 16-row frags per wave (M)
  constexpr int NI = 4;                     // 16-col frags per wave (N)
  __shared__ short Al[128*64];
  __shared__ short Bl[BN*64];
  const int tid = threadIdx.x;
  const int wid = tid >> 6;
  const int lane = tid & 63;
  const int wr = wid / WC, wc = wid % WC;
  const int lrow = lane & 15;
  const int lk   = (lane >> 4) << 3;

  f32x4 acc[MI][NI];
  #pragma unroll
  for (int i=0;i<MI;i++)
    #pragma unroll
    for (int j=0;j<NI;j++) acc[i][j] = (f32x4){0.f,0.f,0.f,0.f};

  const size_t abase = (size_t)blockIdx.y * 128 * lda;
  const size_t bbase = (size_t)blockIdx.x * BN  * ldb;

  for (int kt = 0; kt < K; kt += 64) {
    __syncthreads();
    #pragma unroll
    for (int r = 0; r < 4; ++r) {
      int l2 = (r<<8) + tid;
      int row = l2 >> 3, seg = l2 & 7;
      const short* ga = A + abase + (size_t)row*lda + kt + (seg<<3);
      int lbase = (r<<11) + (wid<<9);
      __builtin_amdgcn_global_load_lds(GPTR(ga), LPTR(Al + lbase), 16, 0, 0);
    }
    #pragma unroll
    for (int r = 0; r < BN/32; ++r) {
      int l2 = (r<<8) + tid;
      int row = l2 >> 3, seg = l2 & 7;
      const short* gb = Bt + bbase + (size_t)row*ldb + kt + (seg<<3);
      int lbase = (r<<11) + (wid<<9);
      __builtin_amdgcn_global_load_lds(GPTR(gb), LPTR(Bl + lbase), 16, 0, 0);
    }
    __syncthreads();

    #pragma unroll
    for (int kk = 0; kk < 64; kk += 32) {
      bf16x8 af[MI], bfr[NI];
      #pragma unroll
      for (int mi=0;mi<MI;mi++){
        int row = wr*(MI*16) + (mi<<4) + lrow;
        af[mi] = *(const bf16x8*)(Al + row*64 + kk + lk);
      }
      #pragma unroll
      for (int ni=0;ni<NI;ni++){
        int row = wc*(NI*16) + (ni<<4) + lrow;
        bfr[ni] = *(const bf16x8*)(Bl + row*64 + kk + lk);
      }
      #pragma unroll
      for (int mi=0;mi<MI;mi++)
        #pragma unroll
        for (int ni=0;ni<NI;ni++)
          acc[mi][ni] = __builtin_amdgcn_mfma_f32_16x16x32_bf16(af[mi], bfr[ni], acc[mi][ni], 0, 0, 0);
    }
  }

  const int crow0 = blockIdx.y*128 + wr*(MI*16);
  const int ccol0 = blockIdx.x*BN  + wc*(NI*16);

  if (EPI == 2) {
    #pragma unroll
    for (int mi=0;mi<MI;mi++){
      #pragma unroll
      for (int p=0;p<NI/2;p++){
        int fcol = (ccol0>>1) + (p<<4) + lrow;
        int rowb = crow0 + (mi<<4) + ((lane>>4)<<2);
        #pragma unroll
        for (int v=0;v<4;v++){
          float g = acc[mi][2*p][v], u = acc[mi][2*p+1][v];
          float a = g * u / (1.0f + __expf(-g));
          ((short*)Cout)[(size_t)(rowb+v)*ldc + fcol] = f2bf(a);
        }
      }
    }
  } else {
    #pragma unroll
    for (int mi=0;mi<MI;mi++){
      #pragma unroll
      for (int ni=0;ni<NI;ni++){
        int col  = ccol0 + (ni<<4) + lrow;
        int rowb = crow0 + (mi<<4) + ((lane>>4)<<2);
        #pragma unroll
        for (int v=0;v<4;v++){
          float val = acc[mi][ni][v];
          int row = rowb + v;
          if (EPI == 0) ((short*)Cout)[(size_t)row*ldc + col] = f2bf(val);
          else          ((float*)Cout)[(size_t)row*ldc + col] += val;
        }
      }
    }
  }
}

// ---------------- in-place rope on qkv block [4096][3072] (q,k cols only) ----------------
__global__ __launch_bounds__(256) void rope_blk_kernel(short* __restrict__ qkv,
                                                       const float* __restrict__ cosT,
                                                       const float* __restrict__ sinT){
  int idx = blockIdx.x*256 + threadIdx.x;   // 4096*16*2*4 = 524288
  int jg  = idx & 3;
  int sel = (idx>>2) & 1;
  int h   = (idx>>3) & 15;
  int row = idx >> 7;                        // 0..4095 (n within batch)
  size_t base = (size_t)row*3072 + sel*1024 + h*64 + jg*16;
  bf16x8 a = *(bf16x8*)(qkv+base);
  bf16x8 b = *(bf16x8*)(qkv+base+8);
  const float* cp = cosT + (row<<5) + (jg<<3);
  const float* sp = sinT + (row<<5) + (jg<<3);
  float4 c0 = *(const float4*)cp, c1 = *(const float4*)(cp+4);
  float4 s0 = *(const float4*)sp, s1 = *(const float4*)(sp+4);
  float cc[8] = {c0.x,c0.y,c0.z,c0.w,c1.x,c1.y,c1.z,c1.w};
  float ss[8] = {s0.x,s0.y,s0.z,s0.w,s1.x,s1.y,s1.z,s1.w};
  bf16x8 oa, ob;
  #pragma unroll
  for (int t=0;t<4;t++){
    float x1 = bf2f(a[2*t]), x2 = bf2f(a[2*t+1]);
    oa[2*t]   = f2bf(x1*cc[t] - x2*ss[t]);
    oa[2*t+1] = f2bf(x1*ss[t] + x2*cc[t]);
    float y1 = bf2f(b[2*t]), y2 = bf2f(b[2*t+1]);
    ob[2*t]   = f2bf(y1*cc[t+4] - y2*ss[t+4]);
    ob[2*t+1] = f2bf(y1*ss[t+4] + y2*cc[t+4]);
  }
  *(bf16x8*)(qkv+base)   = oa;
  *(bf16x8*)(qkv+base+8) = ob;
}

// ---------------- sliding-window attention, LDS-staged, 2 lanes/query ----------------
// grid: dim3(4096/128, 16); block 256. qkv is one batch's [4096][3072].
#define QB_ 128
__global__ __launch_bounds__(256, 3) void attn_kernel(const short* __restrict__ qkv,
                                                      short* __restrict__ o){
  __shared__ short Kl[160*72];
  __shared__ short Vl[160*72];
  const int h  = blockIdx.y;
  const int n0 = blockIdx.x * QB_;
  const int tid = threadIdx.x;

  // stage K,V rows n0-16 .. n0+143 (160 rows, clamped), row stride 72 shorts
  for (int i = tid; i < 1280; i += 256){
    int r = i >> 3, g = i & 7;
    int m = n0 - 16 + r;
    int mc = m < 0 ? 0 : (m > N_-1 ? N_-1 : m);
    const short* gk = qkv + (size_t)mc*3072 + 1024 + h*64 + (g<<3);
    const short* gv = qkv + (size_t)mc*3072 + 2048 + h*64 + (g<<3);
    *(bf16x8*)(Kl + r*72 + (g<<3)) = *(const bf16x8*)gk;
    *(bf16x8*)(Vl + r*72 + (g<<3)) = *(const bf16x8*)gv;
  }
  __syncthreads();

  const int q  = tid >> 1;       // local query 0..127
  const int dh = tid & 1;        // d-half
  const int nc = n0 + q;

  const short* qp = qkv + (size_t)nc*3072 + h*64 + dh*32;
  float qr[32];
  #pragma unroll
  for (int i=0;i<4;i++){
    bf16x8 qv = *(const bf16x8*)(qp + i*8);
    #pragma unroll
    for (int t=0;t<8;t++) qr[i*8+t] = bf2f(qv[t]) * 0.125f;
  }

  float sc[31];
  float mx = -1e30f;
  #pragma unroll
  for (int t=0;t<31;t++){
    int m = nc - 15 + t;
    const short* kp = Kl + (q + 1 + t)*72 + dh*32;
    float dot = 0.f;
    #pragma unroll
    for (int i=0;i<4;i++){
      bf16x8 kv = *(const bf16x8*)(kp + i*8);
      #pragma unroll
      for (int u=0;u<8;u++) dot += qr[i*8+u] * bf2f(kv[u]);
    }
    dot += __shfl_xor(dot, 1, 64);
    bool valid = (m>=0) && (m<N_);
    sc[t] = valid ? dot : -1e30f;
    mx = fmaxf(mx, sc[t]);
  }
  float sum = 0.f;
  #pragma unroll
  for (int t=0;t<31;t++){ sc[t] = __expf(sc[t]-mx); sum += sc[t]; }
  float inv = 1.0f/sum;

  float ov[32];
  #pragma unroll
  for (int i=0;i<32;i++) ov[i]=0.f;
  #pragma unroll
  for (int t=0;t<31;t++){
    const short* vp = Vl + (q + 1 + t)*72 + dh*32;
    float p = sc[t]*inv;
    #pragma unroll
    for (int i=0;i<4;i++){
      bf16x8 vv = *(const bf16x8*)(vp + i*8);
      #pragma unroll
      for (int u=0;u<8;u++) ov[i*8+u] += p * bf2f(vv[u]);
    }
  }
  short* op = o + (size_t)nc*1024 + h*64 + dh*32;
  #pragma unroll
  for (int i=0;i<4;i++){
    bf16x8 wv;
    #pragma unroll
    for (int u=0;u<8;u++) wv[u] = f2bf(ov[i*8+u]);
    *(bf16x8*)(op + i*8) = wv;
  }
}

// ---------------- final rmsnorm + head matmul (V=6), fp32 ----------------
__global__ __launch_bounds__(256) void head_kernel(const float* __restrict__ z,
                                                   const float* __restrict__ fw,
                                                   const float* __restrict__ hw,
                                                   float* __restrict__ out){
  int row = blockIdx.x, tid = threadIdx.x;
  const float* x = z + (size_t)row*D_;
  float4 v = *(const float4*)(x + tid*4);
  float ss = v.x*v.x + v.y*v.y + v.z*v.z + v.w*v.w;
  #pragma unroll
  for (int off=32; off>0; off>>=1) ss += __shfl_down(ss, off, 64);
  __shared__ float red[4];
  if ((tid & 63) == 0) red[tid>>6] = ss;
  __syncthreads();
  float ms = (red[0]+red[1]+red[2]+red[3]) * (1.0f/D_);
  float rs = rsqrtf(ms + 1e-6f);
  float4 wv = *(const float4*)(fw + tid*4);
  float h0 = v.x*rs*wv.x, h1 = v.y*rs*wv.y, h2 = v.z*rs*wv.z, h3 = v.w*rs*wv.w;
  float p[6];
  #pragma unroll
  for (int t=0;t<6;t++){
    const float* hp = hw + (size_t)(tid*4)*6 + t;
    p[t] = h0*hp[0] + h1*hp[6] + h2*hp[12] + h3*hp[18];
  }
  #pragma unroll
  for (int t=0;t<6;t++)
    #pragma unroll
    for (int off=32; off>0; off>>=1) p[t] += __shfl_down(p[t], off, 64);
  __shared__ float wred[4][6];
  if ((tid & 63) == 0)
    #pragma unroll
    for (int t=0;t<6;t++) wred[tid>>6][t] = p[t];
  __syncthreads();
  if (tid < 6)
    out[(size_t)row*6 + tid] = wred[0][tid]+wred[1][tid]+wred[2][tid]+wred[3][tid];
}

extern "C" void kernel_launch(void* const* d_in, const int* in_sizes, int n_in,
                              void* d_out, int out_size, void* d_ws, size_t ws_size,
                              hipStream_t stream)
{
  (void)in_sizes; (void)n_in; (void)out_size; (void)ws_size;
  const float* z_hat  = (const float*)d_in[0];
  const float* source = (const float*)d_in[1];
  const float* wq  = (const float*)d_in[2];
  const float* wk  = (const float*)d_in[3];
  const float* wvp = (const float*)d_in[4];
  const float* wo  = (const float*)d_in[5];
  const float* n1w = (const float*)d_in[6];
  const float* n2w = (const float*)d_in[7];
  const float* w1  = (const float*)d_in[8];
  const float* w3  = (const float*)d_in[9];
  const float* w2  = (const float*)d_in[10];
  const float* fnw = (const float*)d_in[11];
  const float* hw  = (const float*)d_in[12];
  float* out = (float*)d_out;

  // ---- workspace layout (total ≈ 121 MiB, unchanged) ----
  char* ws = (char*)d_ws;
  float* z     = (float*)(ws);                      // 67,108,864
  short* h_b   = (short*)(ws + 67108864);           //  8,388,608  [4096][1024] bf16
  short* qkv_b = (short*)(ws + 75497472);           // 25,165,824  [4096][3072] bf16 (shared with act)
  short* act_b = qkv_b;                             //             [4096][2752] bf16
  short* o_b   = (short*)(ws + 100663296);          //  8,388,608  [4096][1024] bf16
  short* qkvW  = (short*)(ws + 109051904);          //  6,291,456  [3072][1024] (stage A)
  short* woW   = (short*)(ws + 115343360);          //  2,097,152  [1024][1024] (stage A)
  short* w13W  = (short*)(ws + 109051904);          // 11,272,192  [5504][1024] (stage B, reuse)
  short* w2W   = (short*)(ws + 120324096);          //  5,636,096  [1024][2752] (stage B)
  float* cosT  = (float*)(ws + 125960192);          //    524,288
  float* sinT  = (float*)(ws + 126484480);          //    524,288

  dim3 tb(32,8);
  rope_table_kernel<<<512,256,0,stream>>>(cosT, sinT);
  gather_kernel<<<16384,256,0,stream>>>(z_hat, source, z);

  for (int l=0; l<NL_; l++){
    size_t wofs = (size_t)l*D_*D_;
    // ---- stage A weights ----
    tconv_kernel<<<dim3(32,32),tb,0,stream>>>(wq  + wofs, qkvW,               1024,1024,1024, 64,64,0);
    tconv_kernel<<<dim3(32,32),tb,0,stream>>>(wk  + wofs, qkvW + 1024*1024,   1024,1024,1024, 64,64,0);
    tconv_kernel<<<dim3(32,32),tb,0,stream>>>(wvp + wofs, qkvW + 2048*1024,   1024,1024,1024, 64,64,0);
    tconv_kernel<<<dim3(32,32),tb,0,stream>>>(wo  + wofs, woW,                1024,1024,1024, 64,64,0);
    // ---- stage A: per-batch attention path ----
    for (int b=0; b<B_; b++){
      float* zb = z + (size_t)b*N_*D_;
      rmsnorm_kernel<<<N_,256,0,stream>>>(zb, n1w + l*D_, h_b);
      gemm_bt_kernel<0,128><<<dim3(24,32),256,0,stream>>>(h_b,1024, qkvW,1024, qkv_b,3072, 1024);
      rope_blk_kernel<<<2048,256,0,stream>>>(qkv_b, cosT, sinT);
      attn_kernel<<<dim3(N_/QB_,H_),256,0,stream>>>(qkv_b, o_b);
      gemm_bt_kernel<1,64><<<dim3(16,32),256,0,stream>>>(o_b,1024, woW,1024, zb,1024, 1024);
    }
    // ---- stage B weights ----
    tconv_kernel<<<dim3(32,86),tb,0,stream>>>(w1 + (size_t)l*D_*FF_, w13W, 1024,2752,1024, 16,32,0);
    tconv_kernel<<<dim3(32,86),tb,0,stream>>>(w3 + (size_t)l*D_*FF_, w13W, 1024,2752,1024, 16,32,16);
    tconv_kernel<<<dim3(86,32),tb,0,stream>>>(w2 + (size_t)l*FF_*D_, w2W,  2752,1024,2752, 64,64,0);
    // ---- stage B: per-batch FFN ----
    for (int b=0; b<B_; b++){
      float* zb = z + (size_t)b*N_*D_;
      rmsnorm_kernel<<<N_,256,0,stream>>>(zb, n2w + l*D_, h_b);
      gemm_bt_kernel<2,128><<<dim3(43,32),256,0,stream>>>(h_b,1024, w13W,1024, act_b,2752, 1024);
      gemm_bt_kernel<1,64><<<dim3(16,32),256,0,stream>>>(act_b,2752, w2W,2752, zb,1024, 2752);
    }
  }
  head_kernel<<<M_,256,0,stream>>>(z, fnw, hw, out);
}